// Round 1
// baseline (832.015 us; speedup 1.0000x reference)
//
#include <hip/hip_runtime.h>

// ---------- types / helpers ----------
typedef unsigned short u16;
typedef short short8 __attribute__((ext_vector_type(8)));
typedef float f32x4 __attribute__((ext_vector_type(4)));
typedef u16 u16x4 __attribute__((ext_vector_type(4)));

__device__ __forceinline__ u16 f2bf(float f) {
    unsigned int u = __float_as_uint(f);
    u += 0x7fffu + ((u >> 16) & 1u);   // round-to-nearest-even
    return (u16)(u >> 16);
}
__device__ __forceinline__ float bf2f(u16 s) {
    return __uint_as_float(((unsigned int)s) << 16);
}
__device__ __forceinline__ f32x4 mfma16(short8 a, short8 b, f32x4 c) {
    return __builtin_amdgcn_mfma_f32_16x16x32_bf16(a, b, c, 0, 0, 0);
}

// ---------- constants ----------
#define BATCH 2
#define SEQ   2048
#define HID   2048
#define NH    8
#define HD    256
#define MROWS (BATCH * SEQ)   // 4096

// ---------- fp32 -> bf16 convert (vectorized x4) ----------
__global__ void k_cvt(const float* __restrict__ src, u16* __restrict__ dst, int n) {
    int i = (blockIdx.x * 256 + threadIdx.x) * 4;
    if (i >= n) return;
    float4 v = *(const float4*)(src + i);
    u16x4 o; o.x = f2bf(v.x); o.y = f2bf(v.y); o.z = f2bf(v.z); o.w = f2bf(v.w);
    *(u16x4*)(dst + i) = o;
}

// ---------- fp32 [K][Ncols] -> bf16 transposed [N][K], K = 2048 ----------
__global__ void k_cvt_t(const float* __restrict__ W, u16* __restrict__ Wt, int Ncols) {
    int idx = blockIdx.x * 256 + threadIdx.x;       // over N*K
    int n = idx >> 11;                               // /2048
    int k = idx & 2047;
    Wt[idx] = f2bf(W[(size_t)k * Ncols + n]);
}

// ---------- bf16 GEMM: C[M,N] = A[M,K] * Bt[N,K]^T ----------
// 128x128 tile, BK=64, 4 waves each computing 64x64 via 16x16x32 MFMA
template<int OUTF32>
__global__ __launch_bounds__(256) void k_gemm(const u16* __restrict__ A,
                                              const u16* __restrict__ Bt,
                                              u16* __restrict__ Cb,
                                              float* __restrict__ Cf,
                                              int K, int ldc) {
    const int tid  = threadIdx.x;
    const int lane = tid & 63;
    const int wave = tid >> 6;
    const int wrow = (wave >> 1) * 64, wcol = (wave & 1) * 64;
    const int m0 = blockIdx.y * 128, n0 = blockIdx.x * 128;
    const int g = lane >> 4, c = lane & 15;

    __shared__ __align__(16) u16 sA[128][72];  // +8 pad: b128 reads land 2-way (free)
    __shared__ __align__(16) u16 sB[128][72];

    f32x4 acc[4][4] = {};

    for (int k0 = 0; k0 < K; k0 += 64) {
        short8 av[4], bv[4];
#pragma unroll
        for (int i = 0; i < 4; i++) {
            int q = tid + i * 256;              // 1024 chunks of 8 elems
            int r = q >> 3, cc = (q & 7) * 8;
            av[i] = *(const short8*)(A  + (size_t)(m0 + r) * K + k0 + cc);
            bv[i] = *(const short8*)(Bt + (size_t)(n0 + r) * K + k0 + cc);
        }
        __syncthreads();                        // previous tile fully consumed
#pragma unroll
        for (int i = 0; i < 4; i++) {
            int q = tid + i * 256;
            int r = q >> 3, cc = (q & 7) * 8;
            *(short8*)&sA[r][cc] = av[i];
            *(short8*)&sB[r][cc] = bv[i];
        }
        __syncthreads();
#pragma unroll
        for (int ks = 0; ks < 2; ks++) {
            short8 aF[4], bF[4];
#pragma unroll
            for (int t = 0; t < 4; t++) {
                aF[t] = *(const short8*)&sA[wrow + t * 16 + c][ks * 32 + g * 8];
                bF[t] = *(const short8*)&sB[wcol + t * 16 + c][ks * 32 + g * 8];
            }
#pragma unroll
            for (int mt = 0; mt < 4; mt++)
#pragma unroll
                for (int nt = 0; nt < 4; nt++)
                    acc[mt][nt] = mfma16(aF[mt], bF[nt], acc[mt][nt]);
        }
    }
    // epilogue: D layout col=lane&15, row=(lane>>4)*4+r (verified m89)
#pragma unroll
    for (int mt = 0; mt < 4; mt++)
#pragma unroll
        for (int nt = 0; nt < 4; nt++)
#pragma unroll
            for (int r = 0; r < 4; r++) {
                int row = m0 + wrow + mt * 16 + g * 4 + r;
                int col = n0 + wcol + nt * 16 + c;
                float v = acc[mt][nt][r];
                if (OUTF32) Cf[(size_t)row * ldc + col] = v;
                else        Cb[(size_t)row * ldc + col] = f2bf(v);
            }
}

// ---------- RoPE in-place on Q [4096][2048] and K part of KV [4096][512] ----------
__global__ void k_rope(u16* __restrict__ Qb, u16* __restrict__ KVb) {
    int idx = blockIdx.x * 256 + threadIdx.x;
    const int QP = MROWS * NH * 128;   // 4194304 Q pairs
    u16* base; int pos, d;
    if (idx < QP) {
        int row  = idx >> 10;          // /1024 pairs per row
        int rest = idx & 1023;
        int h = rest >> 7; d = rest & 127;
        base = Qb + (size_t)row * HID + h * HD + d;
        pos = row & (SEQ - 1);
    } else {
        int j = idx - QP;              // K pairs: 524288
        int row = j >> 7; d = j & 127;
        base = KVb + (size_t)row * 512 + d;
        pos = row & (SEQ - 1);
    }
    // inv_freq = 10000^(-d/128); ln(10000) = 9.210340372
    float invf = __expf(-(float)d * (9.2103403719761836f / 128.0f));
    float ang = (float)pos * invf;
    float sn, cs;
    sincosf(ang, &sn, &cs);
    float x0 = bf2f(base[0]);
    float x1 = bf2f(base[128]);
    base[0]   = f2bf(x0 * cs - x1 * sn);
    base[128] = f2bf(x1 * cs + x0 * sn);
}

// ---------- causal GQA flash attention ----------
// grid (S/64, B*NH); 4 waves; wave handles 16 q rows; KV tile = 32 rows.
__global__ __launch_bounds__(256) void k_attn(const u16* __restrict__ Q,
                                              const u16* __restrict__ KV,
                                              u16* __restrict__ Oa) {
    const int tid  = threadIdx.x;
    const int lane = tid & 63;
    const int wave = tid >> 6;
    const int g = lane >> 4, c = lane & 15;
    const int qb = blockIdx.x * 64;
    const int b  = blockIdx.y >> 3, h = blockIdx.y & 7;
    const int wq = qb + wave * 16;

    __shared__ __align__(16) u16 sK[32 * 256];      // XOR-swizzled rows (G4 fix)
    __shared__ __align__(16) u16 sVt[256][40];      // transposed V, +8 pad
    __shared__ __align__(16) u16 sP[4][16][40];     // per-wave P transpose buffer

    // Q fragments held in registers for the whole KV loop
    short8 qf[8];
    const size_t qoff = (size_t)(b * SEQ + wq + c) * HID + h * HD;
#pragma unroll
    for (int ks = 0; ks < 8; ks++)
        qf[ks] = *(const short8*)(Q + qoff + ks * 32 + g * 8);

    f32x4 o[16] = {};
    float m[4] = {-1e30f, -1e30f, -1e30f, -1e30f};
    float l[4] = {0.f, 0.f, 0.f, 0.f};

    const int nt = qb / 32 + 2;     // tiles needed to cover causal extent
    for (int t = 0; t < nt; t++) {
        // ---- stage K (swizzled) and V (transposed) ----
        const size_t kvbase = (size_t)(b * SEQ + t * 32) * 512;
#pragma unroll
        for (int i = 0; i < 4; i++) {
            int ch = tid + i * 256;             // 1024 chunks of 8
            int r = ch >> 5, cc = (ch & 31) * 8;
            short8 k8 = *(const short8*)(KV + kvbase + (size_t)r * 512 + cc);
            short8 v8 = *(const short8*)(KV + kvbase + (size_t)r * 512 + 256 + cc);
            int kb = (r * 512 + cc * 2) ^ ((r & 7) << 4);
            *(short8*)((char*)sK + kb) = k8;
#pragma unroll
            for (int j = 0; j < 8; j++) sVt[cc + j][r] = (u16)v8[j];
        }
        __syncthreads();

        // ---- S = Q K^T (two 16-col accs) ----
        f32x4 s0 = {}, s1 = {};
#pragma unroll
        for (int ks = 0; ks < 8; ks++) {
            int d2 = (ks * 32 + g * 8) * 2;
            int b0 = (c * 512 + d2) ^ ((c & 7) << 4);
            int b1 = ((c + 16) * 512 + d2) ^ ((c & 7) << 4);
            short8 kf0 = *(const short8*)((char*)sK + b0);
            short8 kf1 = *(const short8*)((char*)sK + b1);
            s0 = mfma16(qf[ks], kf0, s0);
            s1 = mfma16(qf[ks], kf1, s1);
        }

        // ---- online softmax (rows 4g+r, cols c / c+16 of this tile) ----
#pragma unroll
        for (int r = 0; r < 4; r++) {
            int qr = wq + 4 * g + r;
            float v0 = s0[r] * 0.0625f; if (t * 32 + c      > qr) v0 = -1e30f;
            float v1 = s1[r] * 0.0625f; if (t * 32 + 16 + c > qr) v1 = -1e30f;
            float mx = fmaxf(v0, v1);
            mx = fmaxf(mx, __shfl_xor(mx, 1));
            mx = fmaxf(mx, __shfl_xor(mx, 2));
            mx = fmaxf(mx, __shfl_xor(mx, 4));
            mx = fmaxf(mx, __shfl_xor(mx, 8));
            float mn = fmaxf(m[r], mx);
            float sc = __expf(m[r] - mn);
            float p0 = __expf(v0 - mn);
            float p1 = __expf(v1 - mn);
            float rs = p0 + p1;
            rs += __shfl_xor(rs, 1);
            rs += __shfl_xor(rs, 2);
            rs += __shfl_xor(rs, 4);
            rs += __shfl_xor(rs, 8);
            l[r] = l[r] * sc + rs;
            m[r] = mn;
#pragma unroll
            for (int dt = 0; dt < 16; dt++) o[dt][r] *= sc;
            sP[wave][4 * g + r][c]      = f2bf(p0);
            sP[wave][4 * g + r][16 + c] = f2bf(p1);
        }
        // wave-local LDS RAW: compiler inserts lgkmcnt waits (same array)
        short8 pf = *(const short8*)&sP[wave][c][g * 8];
#pragma unroll
        for (int dt = 0; dt < 16; dt++) {
            short8 vf = *(const short8*)&sVt[dt * 16 + c][g * 8];
            o[dt] = mfma16(pf, vf, o[dt]);
        }
        __syncthreads();   // protect sK/sVt before next stage
    }

    // ---- normalize + store bf16 ----
#pragma unroll
    for (int r = 0; r < 4; r++) {
        float inv = 1.0f / l[r];
        size_t row = (size_t)(b * SEQ + wq + 4 * g + r) * HID + h * HD;
#pragma unroll
        for (int dt = 0; dt < 16; dt++)
            Oa[row + dt * 16 + c] = f2bf(o[dt][r] * inv);
    }
}

// ---------- launch ----------
extern "C" void kernel_launch(void* const* d_in, const int* in_sizes, int n_in,
                              void* d_out, int out_size, void* d_ws, size_t ws_size,
                              hipStream_t stream) {
    const float* hidden = (const float*)d_in[0];
    // d_in[1] = attention_mask: pure causal, applied analytically (exp(-1e9) == 0)
    const float* Wq = (const float*)d_in[2];
    const float* Wk = (const float*)d_in[3];
    const float* Wv = (const float*)d_in[4];
    const float* Wo = (const float*)d_in[5];
    float* out = (float*)d_out;

    char* ws = (char*)d_ws;
    u16* hid_bf = (u16*)(ws);                       // 16 MB
    u16* Wqt    = (u16*)(ws + (16u << 20));         //  8 MB  [2048][2048]
    u16* Wkvt   = (u16*)(ws + (24u << 20));         //  2 MB  [512][2048] (K rows then V rows)
    u16* Wot    = (u16*)(ws + (26u << 20));         //  8 MB  [2048][2048]
    u16* Qb     = (u16*)(ws + (34u << 20));         // 16 MB  [4096][2048]
    u16* KVb    = (u16*)(ws + (50u << 20));         //  4 MB  [4096][512]
    u16* Ab     = (u16*)(ws + (54u << 20));         // 16 MB  [4096][2048]  (end 70 MB)

    // converts / transposes
    k_cvt  <<<8192, 256, 0, stream>>>(hidden, hid_bf, MROWS * HID);
    k_cvt_t<<<16384, 256, 0, stream>>>(Wq, Wqt, 2048);
    k_cvt_t<<<2048, 256, 0, stream>>>(Wk, Wkvt, 256);
    k_cvt_t<<<2048, 256, 0, stream>>>(Wv, Wkvt + (size_t)256 * 2048, 256);
    k_cvt_t<<<16384, 256, 0, stream>>>(Wo, Wot, 2048);

    // projections
    k_gemm<0><<<dim3(16, 32), 256, 0, stream>>>(hid_bf, Wqt,  Qb,  nullptr, 2048, 2048);
    k_gemm<0><<<dim3(4, 32),  256, 0, stream>>>(hid_bf, Wkvt, KVb, nullptr, 2048, 512);

    // rope (Q pairs + K pairs = 4718592, exact multiple of 256)
    k_rope<<<18432, 256, 0, stream>>>(Qb, KVb);

    // attention
    k_attn<<<dim3(32, 16), 256, 0, stream>>>(Qb, KVb, Ab);

    // output projection (fp32 out)
    k_gemm<1><<<dim3(16, 32), 256, 0, stream>>>(Ab, Wot, nullptr, out, 2048, 2048);
}

// Round 2
// 307.691 us; speedup vs baseline: 2.7041x; 2.7041x over previous
//
#include <hip/hip_runtime.h>

// ---------- types / helpers ----------
typedef unsigned short u16;
typedef short short8 __attribute__((ext_vector_type(8)));
typedef float f32x4 __attribute__((ext_vector_type(4)));
typedef u16 u16x4 __attribute__((ext_vector_type(4)));

__device__ __forceinline__ u16 f2bf(float f) {
    unsigned int u = __float_as_uint(f);
    u += 0x7fffu + ((u >> 16) & 1u);   // round-to-nearest-even
    return (u16)(u >> 16);
}
__device__ __forceinline__ float bf2f(u16 s) {
    return __uint_as_float(((unsigned int)s) << 16);
}
__device__ __forceinline__ f32x4 mfma16(short8 a, short8 b, f32x4 c) {
    return __builtin_amdgcn_mfma_f32_16x16x32_bf16(a, b, c, 0, 0, 0);
}

// ---------- constants ----------
#define BATCH 2
#define SEQ   2048
#define HID   2048
#define NH    8
#define HD    256
#define MROWS (BATCH * SEQ)   // 4096

// ---------- fp32 -> bf16 convert (vectorized x4) ----------
__global__ void k_cvt(const float* __restrict__ src, u16* __restrict__ dst, int n) {
    int i = (blockIdx.x * 256 + threadIdx.x) * 4;
    if (i >= n) return;
    float4 v = *(const float4*)(src + i);
    u16x4 o; o.x = f2bf(v.x); o.y = f2bf(v.y); o.z = f2bf(v.z); o.w = f2bf(v.w);
    *(u16x4*)(dst + i) = o;
}

// ---------- fp32 [K][Ncols] -> bf16 transposed [N][K], K = 2048 ----------
__global__ void k_cvt_t(const float* __restrict__ W, u16* __restrict__ Wt, int Ncols) {
    int idx = blockIdx.x * 256 + threadIdx.x;       // over N*K
    int n = idx >> 11;                               // /2048
    int k = idx & 2047;
    Wt[idx] = f2bf(W[(size_t)k * Ncols + n]);
}

// ---------- V transpose: KVb V-half [b][k][d] -> Vt[b][d][perm-k] ----------
// within each 64-k chunk, store position p = perm(j) = (j&15)*4 + (j>>4)
// (attention stores P in the same permuted k order; contraction is order-agnostic)
__global__ void k_vt(const u16* __restrict__ KVb, u16* __restrict__ Vt) {
    int idx = blockIdx.x * 256 + threadIdx.x;  // 2*2048*256 inputs, input-coalesced
    int d = idx & 255;
    int k = (idx >> 8) & 2047;
    int b = idx >> 19;
    u16 v = KVb[((size_t)(b * SEQ + k) << 9) + 256 + d];
    int j = k & 63, chunk = k >> 6;
    int p = ((j & 15) << 2) | (j >> 4);
    Vt[((size_t)(b * 256 + d) << 11) + chunk * 64 + p] = v;
}

// ---------- bf16 GEMM: C[M,N] = A[M,K] * Bt[N,K]^T ----------
// 128x128 tile, BK=64, 4 waves each computing 64x64 via 16x16x32 MFMA
template<int OUTF32>
__global__ __launch_bounds__(256) void k_gemm(const u16* __restrict__ A,
                                              const u16* __restrict__ Bt,
                                              u16* __restrict__ Cb,
                                              float* __restrict__ Cf,
                                              int K, int ldc) {
    const int tid  = threadIdx.x;
    const int lane = tid & 63;
    const int wave = tid >> 6;
    const int wrow = (wave >> 1) * 64, wcol = (wave & 1) * 64;
    const int m0 = blockIdx.y * 128, n0 = blockIdx.x * 128;
    const int g = lane >> 4, c = lane & 15;

    __shared__ __align__(16) u16 sA[128][72];
    __shared__ __align__(16) u16 sB[128][72];

    f32x4 acc[4][4] = {};

    for (int k0 = 0; k0 < K; k0 += 64) {
        short8 av[4], bv[4];
#pragma unroll
        for (int i = 0; i < 4; i++) {
            int q = tid + i * 256;
            int r = q >> 3, cc = (q & 7) * 8;
            av[i] = *(const short8*)(A  + (size_t)(m0 + r) * K + k0 + cc);
            bv[i] = *(const short8*)(Bt + (size_t)(n0 + r) * K + k0 + cc);
        }
        __syncthreads();
#pragma unroll
        for (int i = 0; i < 4; i++) {
            int q = tid + i * 256;
            int r = q >> 3, cc = (q & 7) * 8;
            *(short8*)&sA[r][cc] = av[i];
            *(short8*)&sB[r][cc] = bv[i];
        }
        __syncthreads();
#pragma unroll
        for (int ks = 0; ks < 2; ks++) {
            short8 aF[4], bF[4];
#pragma unroll
            for (int t = 0; t < 4; t++) {
                aF[t] = *(const short8*)&sA[wrow + t * 16 + c][ks * 32 + g * 8];
                bF[t] = *(const short8*)&sB[wcol + t * 16 + c][ks * 32 + g * 8];
            }
#pragma unroll
            for (int mt = 0; mt < 4; mt++)
#pragma unroll
                for (int nt = 0; nt < 4; nt++)
                    acc[mt][nt] = mfma16(aF[mt], bF[nt], acc[mt][nt]);
        }
    }
#pragma unroll
    for (int mt = 0; mt < 4; mt++)
#pragma unroll
        for (int nt = 0; nt < 4; nt++)
#pragma unroll
            for (int r = 0; r < 4; r++) {
                int row = m0 + wrow + mt * 16 + g * 4 + r;
                int col = n0 + wcol + nt * 16 + c;
                float v = acc[mt][nt][r];
                if (OUTF32) Cf[(size_t)row * ldc + col] = v;
                else        Cb[(size_t)row * ldc + col] = f2bf(v);
            }
}

// ---------- RoPE in-place on Q [4096][2048] and K part of KV [4096][512] ----------
__global__ void k_rope(u16* __restrict__ Qb, u16* __restrict__ KVb) {
    int idx = blockIdx.x * 256 + threadIdx.x;
    const int QP = MROWS * NH * 128;   // 4194304 Q pairs
    u16* base; int pos, d;
    if (idx < QP) {
        int row  = idx >> 10;
        int rest = idx & 1023;
        int h = rest >> 7; d = rest & 127;
        base = Qb + (size_t)row * HID + h * HD + d;
        pos = row & (SEQ - 1);
    } else {
        int j = idx - QP;              // K pairs: 524288
        int row = j >> 7; d = j & 127;
        base = KVb + (size_t)row * 512 + d;
        pos = row & (SEQ - 1);
    }
    float invf = __expf(-(float)d * (9.2103403719761836f / 128.0f));
    float ang = (float)pos * invf;
    float sn, cs;
    sincosf(ang, &sn, &cs);
    float x0 = bf2f(base[0]);
    float x1 = bf2f(base[128]);
    base[0]   = f2bf(x0 * cs - x1 * sn);
    base[128] = f2bf(x1 * cs + x0 * sn);
}

// ---------- causal GQA flash attention, v2 ----------
// 512 blocks, 4 waves; wave = 16 q rows; KV tile = 64; XOR-swizzled LDS.
__global__ __launch_bounds__(256) void k_attn(const u16* __restrict__ Q,
                                              const u16* __restrict__ KV,
                                              const u16* __restrict__ Vt,
                                              u16* __restrict__ Oa) {
    const int tid  = threadIdx.x;
    const int lane = tid & 63;
    const int wave = tid >> 6;
    const int g = lane >> 4, c = lane & 15;

    // pair q-tile a with 31-a on the two per-CU block slots -> ~uniform CU load
    const int bid   = blockIdx.x;
    const int bh    = bid & 15;
    const int qpair = (bid >> 4) & 15;
    const int qidx  = (bid >> 8) ? (31 - qpair) : qpair;
    const int qb    = qidx << 6;
    const int b = bh >> 3, h = bh & 7;
    const int wq = qb + wave * 16;

    __shared__ __align__(16) u16 sK[64 * 256];     // swizzled: byte ^= (row&7)<<4
    __shared__ __align__(16) u16 sVt[256 * 64];    // V^T (perm-k), swizzled
    __shared__ __align__(16) u16 sP[4 * 16 * 64];  // per-wave P (perm-k), swizzled

    char* const pK = (char*)sK;
    char* const pV = (char*)sVt;
    char* const pP = (char*)sP + wave * 2048;

    // Q fragments held in registers (A-operand rows = wq + c)
    short8 qf[8];
    const size_t qoff = (size_t)(b * SEQ + wq + c) * HID + h * HD;
#pragma unroll
    for (int ks = 0; ks < 8; ks++)
        qf[ks] = *(const short8*)(Q + qoff + ks * 32 + g * 8);

    f32x4 o[16] = {};
    float m[4] = {-1e30f, -1e30f, -1e30f, -1e30f};
    float l[4] = {0.f, 0.f, 0.f, 0.f};
    const int swz = (c & 7) << 4;

    const int nt = qidx + 1;
    for (int t = 0; t < nt; t++) {
        // ---- global -> regs (issued before barrier to hide latency) ----
        short8 kv8[8], vv8[8];
        const size_t krow = (size_t)(b * SEQ + t * 64) * 512;
        const size_t vrow = (size_t)(b * 256) * 2048 + t * 64;
#pragma unroll
        for (int i = 0; i < 8; i++) {
            int ch = tid + i * 256;
            kv8[i] = *(const short8*)(KV + krow + (size_t)(ch >> 5) * 512 + (ch & 31) * 8);
            vv8[i] = *(const short8*)(Vt + vrow + (size_t)(ch >> 3) * 2048 + (ch & 7) * 8);
        }
        __syncthreads();                       // previous tile fully consumed
#pragma unroll
        for (int i = 0; i < 8; i++) {
            int ch = tid + i * 256;
            int kr = ch >> 5, kc2 = (ch & 31) * 16;
            *(short8*)(pK + ((kr * 512 + kc2) ^ ((kr & 7) << 4))) = kv8[i];
            int vr = ch >> 3, vc2 = (ch & 7) * 16;
            *(short8*)(pV + ((vr * 128 + vc2) ^ ((vr & 7) << 4))) = vv8[i];
        }
        __syncthreads();

        // ---- S = Q K^T : 4 col-fragments x K=256 ----
        f32x4 s[4] = {};
#pragma unroll
        for (int ks = 0; ks < 8; ks++) {
            short8 kf0 = *(const short8*)(pK + (((c     ) * 512 + ks * 64 + 16 * g) ^ swz));
            short8 kf1 = *(const short8*)(pK + (((c + 16) * 512 + ks * 64 + 16 * g) ^ swz));
            short8 kf2 = *(const short8*)(pK + (((c + 32) * 512 + ks * 64 + 16 * g) ^ swz));
            short8 kf3 = *(const short8*)(pK + (((c + 48) * 512 + ks * 64 + 16 * g) ^ swz));
            s[0] = mfma16(qf[ks], kf0, s[0]);
            s[1] = mfma16(qf[ks], kf1, s[1]);
            s[2] = mfma16(qf[ks], kf2, s[2]);
            s[3] = mfma16(qf[ks], kf3, s[3]);
        }

        // ---- online softmax; P stored perm-k: cols {c,c+16,c+32,c+48} -> 4c..4c+3
        const bool diag = (t == nt - 1);
#pragma unroll
        for (int r = 0; r < 4; r++) {
            int qr = wq + 4 * g + r;
            float v0 = s[0][r] * 0.0625f;
            float v1 = s[1][r] * 0.0625f;
            float v2 = s[2][r] * 0.0625f;
            float v3 = s[3][r] * 0.0625f;
            if (diag) {
                int col = t * 64 + c;
                if (col      > qr) v0 = -1e30f;
                if (col + 16 > qr) v1 = -1e30f;
                if (col + 32 > qr) v2 = -1e30f;
                if (col + 48 > qr) v3 = -1e30f;
            }
            float mx = fmaxf(fmaxf(v0, v1), fmaxf(v2, v3));
            mx = fmaxf(mx, __shfl_xor(mx, 1));
            mx = fmaxf(mx, __shfl_xor(mx, 2));
            mx = fmaxf(mx, __shfl_xor(mx, 4));
            mx = fmaxf(mx, __shfl_xor(mx, 8));
            float mn = fmaxf(m[r], mx);
            float sc = __expf(m[r] - mn);
            float p0 = __expf(v0 - mn);
            float p1 = __expf(v1 - mn);
            float p2 = __expf(v2 - mn);
            float p3 = __expf(v3 - mn);
            float rs = (p0 + p1) + (p2 + p3);
            rs += __shfl_xor(rs, 1);
            rs += __shfl_xor(rs, 2);
            rs += __shfl_xor(rs, 4);
            rs += __shfl_xor(rs, 8);
            l[r] = l[r] * sc + rs;
            m[r] = mn;
#pragma unroll
            for (int dt = 0; dt < 16; dt++) o[dt][r] *= sc;
            u16x4 pk; pk.x = f2bf(p0); pk.y = f2bf(p1); pk.z = f2bf(p2); pk.w = f2bf(p3);
            int row = 4 * g + r;
            *(u16x4*)(pP + ((row * 128 + 8 * c) ^ ((row & 7) << 4))) = pk;
        }

        // ---- O += P V (A = P rows q, B = V^T rows d; both perm-k) ----
        short8 pf0 = *(const short8*)(pP + ((c * 128      + 16 * g) ^ swz));
        short8 pf1 = *(const short8*)(pP + ((c * 128 + 64 + 16 * g) ^ swz));
#pragma unroll
        for (int dt = 0; dt < 16; dt++) {
            short8 vf0 = *(const short8*)(pV + dt * 2048 + ((c * 128      + 16 * g) ^ swz));
            short8 vf1 = *(const short8*)(pV + dt * 2048 + ((c * 128 + 64 + 16 * g) ^ swz));
            o[dt] = mfma16(pf0, vf0, o[dt]);
            o[dt] = mfma16(pf1, vf1, o[dt]);
        }
    }

    // ---- normalize + store bf16 ----
#pragma unroll
    for (int r = 0; r < 4; r++) {
        float inv = 1.0f / l[r];
        size_t rowo = (size_t)(b * SEQ + wq + 4 * g + r) * HID + h * HD;
#pragma unroll
        for (int dt = 0; dt < 16; dt++)
            Oa[rowo + dt * 16 + c] = f2bf(o[dt][r] * inv);
    }
}

// ---------- launch ----------
extern "C" void kernel_launch(void* const* d_in, const int* in_sizes, int n_in,
                              void* d_out, int out_size, void* d_ws, size_t ws_size,
                              hipStream_t stream) {
    const float* hidden = (const float*)d_in[0];
    // d_in[1] = attention_mask: pure causal, applied analytically (exp(-1e9) == 0)
    const float* Wq = (const float*)d_in[2];
    const float* Wk = (const float*)d_in[3];
    const float* Wv = (const float*)d_in[4];
    const float* Wo = (const float*)d_in[5];
    float* out = (float*)d_out;

    char* ws = (char*)d_ws;
    u16* hid_bf = (u16*)(ws);                       // 16 MB (dead after GEMMs)
    u16* Wqt    = (u16*)(ws + (16u << 20));         //  8 MB
    u16* Wkvt   = (u16*)(ws + (24u << 20));         //  2 MB
    u16* Wot    = (u16*)(ws + (26u << 20));         //  8 MB
    u16* Qb     = (u16*)(ws + (34u << 20));         // 16 MB
    u16* KVb    = (u16*)(ws + (50u << 20));         //  4 MB
    u16* Ab     = (u16*)(ws + (54u << 20));         // 16 MB (end 70 MB)
    u16* Vtg    = (u16*)(ws);                       //  2 MB, reuses hid_bf region
                                                    // (written strictly after last hid_bf use,
                                                    //  rewritten from scratch every launch)

    k_cvt  <<<8192, 256, 0, stream>>>(hidden, hid_bf, MROWS * HID);
    k_cvt_t<<<16384, 256, 0, stream>>>(Wq, Wqt, 2048);
    k_cvt_t<<<2048, 256, 0, stream>>>(Wk, Wkvt, 256);
    k_cvt_t<<<2048, 256, 0, stream>>>(Wv, Wkvt + (size_t)256 * 2048, 256);
    k_cvt_t<<<16384, 256, 0, stream>>>(Wo, Wot, 2048);

    k_gemm<0><<<dim3(16, 32), 256, 0, stream>>>(hid_bf, Wqt,  Qb,  nullptr, 2048, 2048);
    k_gemm<0><<<dim3(4, 32),  256, 0, stream>>>(hid_bf, Wkvt, KVb, nullptr, 2048, 512);

    k_rope<<<18432, 256, 0, stream>>>(Qb, KVb);
    k_vt  <<<4096, 256, 0, stream>>>(KVb, Vtg);     // after GEMMs: hid_bf region now free

    k_attn<<<512, 256, 0, stream>>>(Qb, KVb, Vtg, Ab);

    k_gemm<1><<<dim3(16, 32), 256, 0, stream>>>(Ab, Wot, nullptr, out, 2048, 2048);
}